// Round 1
// baseline (181.077 us; speedup 1.0000x reference)
//
#include <hip/hip_runtime.h>
#include <math.h>

// Row-wise argmax over last dim: input (16,512,32000) f32 -> output (16,512,1) f32 (index).
// Softmax over the last dim is monotone, so argmax(softmax(x)) == argmax(x).

#define ROW_LEN   32000
#define ROW_VEC4  (ROW_LEN / 4)   // 8000
#define BLOCK     256

__global__ __launch_bounds__(BLOCK) void argmax_rows_kernel(
    const float* __restrict__ in, float* __restrict__ out)
{
    const int row = blockIdx.x;
    const float4* __restrict__ rp4 =
        reinterpret_cast<const float4*>(in + (size_t)row * ROW_LEN);

    const int tid = threadIdx.x;

    float best = -INFINITY;
    int   bidx = 0;

    // Each thread walks indices in increasing order, so strict '>' gives
    // first-occurrence semantics within a thread.
    for (int i = tid; i < ROW_VEC4; i += BLOCK) {
        float4 v = rp4[i];
        const int base = i * 4;
        if (v.x > best) { best = v.x; bidx = base;     }
        if (v.y > best) { best = v.y; bidx = base + 1; }
        if (v.z > best) { best = v.z; bidx = base + 2; }
        if (v.w > best) { best = v.w; bidx = base + 3; }
    }

    // Wave-level reduction (64 lanes). Tie -> smaller index (first occurrence).
    #pragma unroll
    for (int off = 32; off > 0; off >>= 1) {
        float ov = __shfl_down(best, off);
        int   oi = __shfl_down(bidx, off);
        if (ov > best || (ov == best && oi < bidx)) { best = ov; bidx = oi; }
    }

    // Cross-wave reduction via LDS (BLOCK/64 = 4 partials).
    __shared__ float s_val[BLOCK / 64];
    __shared__ int   s_idx[BLOCK / 64];

    const int lane = tid & 63;
    const int wave = tid >> 6;
    if (lane == 0) { s_val[wave] = best; s_idx[wave] = bidx; }
    __syncthreads();

    if (tid == 0) {
        float fb = s_val[0];
        int   fi = s_idx[0];
        #pragma unroll
        for (int w = 1; w < BLOCK / 64; ++w) {
            const float ov = s_val[w];
            const int   oi = s_idx[w];
            if (ov > fb || (ov == fb && oi < fi)) { fb = ov; fi = oi; }
        }
        out[row] = (float)fi;
    }
}

extern "C" void kernel_launch(void* const* d_in, const int* in_sizes, int n_in,
                              void* d_out, int out_size, void* d_ws, size_t ws_size,
                              hipStream_t stream) {
    (void)in_sizes; (void)n_in; (void)d_ws; (void)ws_size;
    const float* in = (const float*)d_in[0];
    float* out = (float*)d_out;

    const int n_rows = out_size;  // 16 * 512 = 8192
    argmax_rows_kernel<<<n_rows, BLOCK, 0, stream>>>(in, out);
}

// Round 2
// 156.959 us; speedup vs baseline: 1.1537x; 1.1537x over previous
//
#include <hip/hip_runtime.h>
#include <math.h>

// Row-wise argmax over last dim: input (16,512,32000) f32 -> output (16,512,1) f32 (index).
// Softmax over the last dim is monotone, so argmax(softmax(x)) == argmax(x).
//
// R2: 4 independent accumulator slots (ILP — break the serial compare chain,
// keep 4 loads in flight per iteration) + nontemporal loads (read-once stream,
// don't allocate in cache).

#define ROW_LEN   32000
#define ROW_VEC4  (ROW_LEN / 4)   // 8000
#define BLOCK     256

typedef float f32x4 __attribute__((ext_vector_type(4)));

__device__ __forceinline__ void upd(float v, int j, float& best, int& idx) {
    // strict '>' keeps first occurrence within a slot (indices increase over time)
    if (v > best) { best = v; idx = j; }
}

__global__ __launch_bounds__(BLOCK) void argmax_rows_kernel(
    const float* __restrict__ in, float* __restrict__ out)
{
    const int row = blockIdx.x;
    const f32x4* __restrict__ rp4 =
        reinterpret_cast<const f32x4*>(in + (size_t)row * ROW_LEN);

    const int tid = threadIdx.x;

    float bA = -INFINITY, bB = -INFINITY, bC = -INFINITY, bD = -INFINITY;
    int   iA = 0, iB = 0, iC = 0, iD = 0;

    // Slots A,B,C,D handle vec4 indices i, i+256, i+512, i+768; stride 1024.
    // For ROW_VEC4=8000: slots A,B,C always in-bounds; D needs a check on the
    // last iteration only.
    for (int i = tid; i < ROW_VEC4; i += 4 * BLOCK) {
        const int ja = i;
        const int jb = i + BLOCK;
        const int jc = i + 2 * BLOCK;
        const int jd = i + 3 * BLOCK;
        const bool haveD = jd < ROW_VEC4;

        f32x4 va = __builtin_nontemporal_load(rp4 + ja);
        f32x4 vb = __builtin_nontemporal_load(rp4 + jb);
        f32x4 vc = __builtin_nontemporal_load(rp4 + jc);
        f32x4 vd;
        if (haveD) vd = __builtin_nontemporal_load(rp4 + jd);

        upd(va[0], ja*4,   bA, iA); upd(va[1], ja*4+1, bA, iA);
        upd(va[2], ja*4+2, bA, iA); upd(va[3], ja*4+3, bA, iA);

        upd(vb[0], jb*4,   bB, iB); upd(vb[1], jb*4+1, bB, iB);
        upd(vb[2], jb*4+2, bB, iB); upd(vb[3], jb*4+3, bB, iB);

        upd(vc[0], jc*4,   bC, iC); upd(vc[1], jc*4+1, bC, iC);
        upd(vc[2], jc*4+2, bC, iC); upd(vc[3], jc*4+3, bC, iC);

        if (haveD) {
            upd(vd[0], jd*4,   bD, iD); upd(vd[1], jd*4+1, bD, iD);
            upd(vd[2], jd*4+2, bD, iD); upd(vd[3], jd*4+3, bD, iD);
        }
    }

    // Merge the 4 slots. Tie -> smaller index (first occurrence).
    float best = bA; int bidx = iA;
    if (bB > best || (bB == best && iB < bidx)) { best = bB; bidx = iB; }
    if (bC > best || (bC == best && iC < bidx)) { best = bC; bidx = iC; }
    if (bD > best || (bD == best && iD < bidx)) { best = bD; bidx = iD; }

    // Wave-level reduction (64 lanes).
    #pragma unroll
    for (int off = 32; off > 0; off >>= 1) {
        float ov = __shfl_down(best, off);
        int   oi = __shfl_down(bidx, off);
        if (ov > best || (ov == best && oi < bidx)) { best = ov; bidx = oi; }
    }

    // Cross-wave reduction via LDS (BLOCK/64 = 4 partials).
    __shared__ float s_val[BLOCK / 64];
    __shared__ int   s_idx[BLOCK / 64];

    const int lane = tid & 63;
    const int wave = tid >> 6;
    if (lane == 0) { s_val[wave] = best; s_idx[wave] = bidx; }
    __syncthreads();

    if (tid == 0) {
        float fb = s_val[0];
        int   fi = s_idx[0];
        #pragma unroll
        for (int w = 1; w < BLOCK / 64; ++w) {
            const float ov = s_val[w];
            const int   oi = s_idx[w];
            if (ov > fb || (ov == fb && oi < fi)) { fb = ov; fi = oi; }
        }
        out[row] = (float)fi;
    }
}

extern "C" void kernel_launch(void* const* d_in, const int* in_sizes, int n_in,
                              void* d_out, int out_size, void* d_ws, size_t ws_size,
                              hipStream_t stream) {
    (void)in_sizes; (void)n_in; (void)d_ws; (void)ws_size;
    const float* in = (const float*)d_in[0];
    float* out = (float*)d_out;

    const int n_rows = out_size;  // 16 * 512 = 8192
    argmax_rows_kernel<<<n_rows, BLOCK, 0, stream>>>(in, out);
}